// Round 1
// baseline (388.982 us; speedup 1.0000x reference)
//
#include <hip/hip_runtime.h>
#include <math.h>

// Problem constants (from reference setup_inputs): B=4, C=32, H=W=256
#define B_N 4
#define C_N 32
#define H_N 256
#define W_N 256
#define NFFT 256
#define PI_D 3.14159265358979323846

__device__ __forceinline__ float2 cmul(float2 a, float2 b) {
    return make_float2(a.x * b.x - a.y * b.y, a.x * b.y + a.y * b.x);
}

// ---------------- K0: chirp tables (double precision, one tiny block) --------
__global__ void chirp_init(const float* __restrict__ alpha_p,
                           float2* __restrict__ c1, float2* __restrict__ c2,
                           float* __restrict__ scl) {
    int j = threadIdx.x;  // 0..255
    double a = (double)alpha_p[0];
    a = fmin(fmax(a, 1e-4), 2.0 - 1e-4);
    double alpha = a * PI_D / 2.0;
    double tan_a2 = tan(a * PI_D / 4.0);
    double sin_a = sin(alpha);
    double n = (double)(j - NFFT / 2);
    double p1 = -PI_D * n * n * tan_a2 / (double)NFFT;
    c1[j] = make_float2((float)cos(p1), (float)sin(p1));
    double p2 = -PI_D * n * n / ((double)NFFT * sin_a);
    c2[j] = make_float2((float)cos(p2), (float)sin(p2));
    if (j == 0) scl[0] = (float)(1.0 / sqrt(fabs(sin_a) + 1e-12));
}

// ---------------- 256-pt radix-2 DIT FFT in LDS ------------------------------
// s[] must hold input in bit-reversed order; output in natural order.
// 128 threads, one butterfly each per stage.
__device__ void fft256(float2* s, const float2* tw, int tid) {
    #pragma unroll
    for (int st = 1; st <= 8; ++st) {
        __syncthreads();
        int half = 1 << (st - 1);
        int k = tid & (half - 1);
        int j0 = ((tid >> (st - 1)) << st) + k;
        float2 wt = tw[k << (8 - st)];
        float2 a = s[j0];
        float2 b = cmul(s[j0 + half], wt);
        s[j0]        = make_float2(a.x + b.x, a.y + b.y);
        s[j0 + half] = make_float2(a.x - b.x, a.y - b.y);
    }
    __syncthreads();
}

__device__ __forceinline__ int brev8(int j) {
    return (int)(__brev((unsigned)j) >> 24);
}

// ---------------- K1: FRFT along W (rows), real input -> complex Y -----------
__global__ void frft_rows(const float* __restrict__ x,
                          const float2* __restrict__ c1,
                          const float2* __restrict__ c2,
                          const float* __restrict__ scl,
                          float2* __restrict__ Y) {
    __shared__ float2 s[NFFT];
    __shared__ float2 tw[NFFT / 2];
    int tid = threadIdx.x;  // 0..127
    long long row = blockIdx.x;  // b*C*H + c*H + h
    const float* xr = x + row * NFFT;

    // twiddles: tw[j] = exp(-2*pi*i*j/256)
    {
        float ang = -(float)(PI_D / 128.0) * (float)tid;
        float sn, cs;
        __sincosf(ang, &sn, &cs);
        tw[tid] = make_float2(cs, sn);
    }

    // load with ifftshift, multiply by c1, store bit-reversed
    #pragma unroll
    for (int j = tid; j < NFFT; j += 128) {
        float xv = xr[j ^ 128];
        float2 cc = c1[j];
        s[brev8(j)] = make_float2(xv * cc.x, xv * cc.y);
    }
    fft256(s, tw, tid);

    // multiply by c2, conj, re-permute for inverse FFT
    float2 v0, v1;
    {
        float2 t = cmul(s[tid], c2[tid]);
        v0 = make_float2(t.x, -t.y);
        t = cmul(s[tid + 128], c2[tid + 128]);
        v1 = make_float2(t.x, -t.y);
    }
    __syncthreads();
    s[brev8(tid)] = v0;
    s[brev8(tid + 128)] = v1;
    fft256(s, tw, tid);

    float sc = scl[0] * (1.0f / (float)NFFT);
    #pragma unroll
    for (int j = tid; j < NFFT; j += 128) {
        float2 g = make_float2(s[j].x, -s[j].y);  // conj -> ifft*N
        float2 yv = cmul(g, c1[j]);
        Y[row * NFFT + (j ^ 128)] = make_float2(yv.x * sc, yv.y * sc);
    }
}

// ---------------- K2: FRFT along H (columns), complex in-place ---------------
__global__ void frft_cols(float2* __restrict__ Y,
                          const float2* __restrict__ c1,
                          const float2* __restrict__ c2,
                          const float* __restrict__ scl) {
    __shared__ float2 s[NFFT];
    __shared__ float2 tw[NFFT / 2];
    int tid = threadIdx.x;  // 0..127
    int blk = blockIdx.x;   // bc * W + wcol
    int wcol = blk & (W_N - 1);
    long long bc = blk >> 8;
    float2* base = Y + bc * (long long)(H_N * W_N) + wcol;

    {
        float ang = -(float)(PI_D / 128.0) * (float)tid;
        float sn, cs;
        __sincosf(ang, &sn, &cs);
        tw[tid] = make_float2(cs, sn);
    }

    #pragma unroll
    for (int j = tid; j < NFFT; j += 128) {
        float2 xv = base[(long long)(j ^ 128) * W_N];
        s[brev8(j)] = cmul(xv, c1[j]);
    }
    fft256(s, tw, tid);

    float2 v0, v1;
    {
        float2 t = cmul(s[tid], c2[tid]);
        v0 = make_float2(t.x, -t.y);
        t = cmul(s[tid + 128], c2[tid + 128]);
        v1 = make_float2(t.x, -t.y);
    }
    __syncthreads();
    s[brev8(tid)] = v0;
    s[brev8(tid + 128)] = v1;
    fft256(s, tw, tid);

    float sc = scl[0] * (1.0f / (float)NFFT);
    #pragma unroll
    for (int j = tid; j < NFFT; j += 128) {
        float2 g = make_float2(s[j].x, -s[j].y);
        float2 yv = cmul(g, c1[j]);
        base[(long long)(j ^ 128) * W_N] = make_float2(yv.x * sc, yv.y * sc);
    }
}

// ---------------- K3: magnitude/phase + 1x1 conv -----------------------------
__global__ void mag_ang_conv(const float2* __restrict__ Y,
                             const float* __restrict__ wmat,
                             float* __restrict__ out) {
    __shared__ float wl[C_N * 2 * C_N];  // 32*64 = 2048 floats
    int tid = threadIdx.x;
    for (int i = tid; i < C_N * 2 * C_N; i += 256) wl[i] = wmat[i];
    __syncthreads();

    int p = blockIdx.x * 256 + tid;  // pixel index in B*H*W
    int b = p >> 16;                 // H*W = 65536
    int hw = p & 65535;
    const float2* yb = Y + (long long)b * C_N * (H_N * W_N) + hw;

    float acc[C_N];
    #pragma unroll
    for (int o = 0; o < C_N; ++o) acc[o] = 0.0f;

    for (int c = 0; c < C_N; ++c) {
        float2 v = yb[(long long)c * (H_N * W_N)];
        float mag = sqrtf(v.x * v.x + v.y * v.y);
        float ang = atan2f(v.y, v.x) * (float)(1.0 / PI_D);
        #pragma unroll
        for (int o = 0; o < C_N; ++o)
            acc[o] += wl[o * 64 + c] * mag + wl[o * 64 + C_N + c] * ang;
    }

    float* ob = out + (long long)b * C_N * (H_N * W_N) + hw;
    for (int o = 0; o < C_N; ++o)
        ob[(long long)o * (H_N * W_N)] = acc[o];
}

// ---------------- launch -----------------------------------------------------
extern "C" void kernel_launch(void* const* d_in, const int* in_sizes, int n_in,
                              void* d_out, int out_size, void* d_ws, size_t ws_size,
                              hipStream_t stream) {
    const float* x     = (const float*)d_in[0];
    const float* alpha = (const float*)d_in[1];
    const float* wmat  = (const float*)d_in[2];
    float* out = (float*)d_out;

    char* ws = (char*)d_ws;
    float2* c1  = (float2*)(ws);                 // 256 float2 = 2048 B
    float2* c2  = (float2*)(ws + 2048);          // 256 float2 = 2048 B
    float*  scl = (float*)(ws + 4096);           // 1 float
    float2* Y   = (float2*)(ws + 8192);          // B*C*H*W float2 = 64 MiB

    chirp_init<<<1, 256, 0, stream>>>(alpha, c1, c2, scl);

    int nrows = B_N * C_N * H_N;  // 32768
    frft_rows<<<nrows, 128, 0, stream>>>(x, c1, c2, scl, Y);

    int ncols = B_N * C_N * W_N;  // 32768
    frft_cols<<<ncols, 128, 0, stream>>>(Y, c1, c2, scl);

    int npix = B_N * H_N * W_N;   // 262144
    mag_ang_conv<<<npix / 256, 256, 0, stream>>>(Y, wmat, out);
}

// Round 2
// 254.763 us; speedup vs baseline: 1.5268x; 1.5268x over previous
//
#include <hip/hip_runtime.h>
#include <math.h>

// Problem constants (from reference setup_inputs): B=4, C=32, H=W=256
#define B_N 4
#define C_N 32
#define H_N 256
#define W_N 256
#define NFFT 256
#define PI_D 3.14159265358979323846
#define TILE 16
#define LDS_STRIDE 257  // pad +1: col stride 257 float2 = 514 dwords, 514%32=2 -> conflict-free across 16 cols

__device__ __forceinline__ float2 cmul(float2 a, float2 b) {
    return make_float2(a.x * b.x - a.y * b.y, a.x * b.y + a.y * b.x);
}

__device__ __forceinline__ int brev8(int j) {
    return (int)(__brev((unsigned)j) >> 24);
}

// ---------------- K0: chirp tables (double precision, one tiny block) --------
__global__ void chirp_init(const float* __restrict__ alpha_p,
                           float2* __restrict__ c1, float2* __restrict__ c2,
                           float* __restrict__ scl) {
    int j = threadIdx.x;  // 0..255
    double a = (double)alpha_p[0];
    a = fmin(fmax(a, 1e-4), 2.0 - 1e-4);
    double alpha = a * PI_D / 2.0;
    double tan_a2 = tan(a * PI_D / 4.0);
    double sin_a = sin(alpha);
    double n = (double)(j - NFFT / 2);
    double p1 = -PI_D * n * n * tan_a2 / (double)NFFT;
    c1[j] = make_float2((float)cos(p1), (float)sin(p1));
    double p2 = -PI_D * n * n / ((double)NFFT * sin_a);
    c2[j] = make_float2((float)cos(p2), (float)sin(p2));
    if (j == 0) scl[0] = (float)(1.0 / sqrt(fabs(sin_a) + 1e-12));
}

// ---------------- 256-pt radix-2 DIT FFT in LDS (single row, 128 thr) --------
__device__ void fft256(float2* s, const float2* tw, int tid) {
    #pragma unroll
    for (int st = 1; st <= 8; ++st) {
        __syncthreads();
        int half = 1 << (st - 1);
        int k = tid & (half - 1);
        int j0 = ((tid >> (st - 1)) << st) + k;
        float2 wt = tw[k << (8 - st)];
        float2 a = s[j0];
        float2 b = cmul(s[j0 + half], wt);
        s[j0]        = make_float2(a.x + b.x, a.y + b.y);
        s[j0 + half] = make_float2(a.x - b.x, a.y - b.y);
    }
    __syncthreads();
}

// ---------------- K1: FRFT along W (rows), real input -> complex Y -----------
__global__ void frft_rows(const float* __restrict__ x,
                          const float2* __restrict__ c1,
                          const float2* __restrict__ c2,
                          const float* __restrict__ scl,
                          float2* __restrict__ Y) {
    __shared__ float2 s[NFFT];
    __shared__ float2 tw[NFFT / 2];
    int tid = threadIdx.x;  // 0..127
    long long row = blockIdx.x;  // b*C*H + c*H + h
    const float* xr = x + row * NFFT;

    {
        float ang = -(float)(PI_D / 128.0) * (float)tid;
        float sn, cs;
        __sincosf(ang, &sn, &cs);
        tw[tid] = make_float2(cs, sn);
    }

    #pragma unroll
    for (int j = tid; j < NFFT; j += 128) {
        float xv = xr[j ^ 128];
        float2 cc = c1[j];
        s[brev8(j)] = make_float2(xv * cc.x, xv * cc.y);
    }
    fft256(s, tw, tid);

    float2 v0, v1;
    {
        float2 t = cmul(s[tid], c2[tid]);
        v0 = make_float2(t.x, -t.y);
        t = cmul(s[tid + 128], c2[tid + 128]);
        v1 = make_float2(t.x, -t.y);
    }
    __syncthreads();
    s[brev8(tid)] = v0;
    s[brev8(tid + 128)] = v1;
    fft256(s, tw, tid);

    float sc = scl[0] * (1.0f / (float)NFFT);
    #pragma unroll
    for (int j = tid; j < NFFT; j += 128) {
        float2 g = make_float2(s[j].x, -s[j].y);  // conj -> ifft*N
        float2 yv = cmul(g, c1[j]);
        Y[row * NFFT + (j ^ 128)] = make_float2(yv.x * sc, yv.y * sc);
    }
}

// ---------------- K2: FRFT along H, tiled: 16 columns per block --------------
// Block: 256 threads. Grid: B*C*(W/TILE) = 2048. Coalesced 128B row segments.
__global__ __launch_bounds__(256) void frft_cols_tiled(
        float2* __restrict__ Y,
        const float2* __restrict__ c1,
        const float2* __restrict__ c2,
        const float* __restrict__ scl) {
    __shared__ float2 s[TILE * LDS_STRIDE];   // 16 cols x 257 (padded) = 32.9 KB
    __shared__ float2 tw[NFFT / 2];
    int tid = threadIdx.x;       // 0..255
    int c = tid & (TILE - 1);    // column within tile
    int g = tid >> 4;            // 0..15 group (row / butterfly subindex)

    int blk = blockIdx.x;
    int w0 = (blk & (W_N / TILE - 1)) * TILE;
    long long bc = blk >> 4;     // b*C + c index
    float2* base = Y + bc * (long long)(H_N * W_N) + w0;

    if (tid < 128) {
        float ang = -(float)(PI_D / 128.0) * (float)tid;
        float sn, cs;
        __sincosf(ang, &sn, &cs);
        tw[tid] = make_float2(cs, sn);
    }

    // ---- load: ifftshift + x c1, store bit-reversed into padded [col][row] --
    #pragma unroll
    for (int r = 0; r < 16; ++r) {
        int j = g + 16 * r;                       // logical index 0..255
        float2 xv = base[(long long)(j ^ 128) * W_N + c];
        s[c * LDS_STRIDE + brev8(j)] = cmul(xv, c1[j]);
    }

    // ---- forward FFT: 16 cols x 128 butterflies, 8 per thread per stage ----
    #pragma unroll
    for (int st = 1; st <= 8; ++st) {
        __syncthreads();
        int half = 1 << (st - 1);
        #pragma unroll
        for (int i = 0; i < 8; ++i) {
            int b = g + 16 * i;                   // butterfly index 0..127
            int k = b & (half - 1);
            int j0 = ((b >> (st - 1)) << st) + k;
            float2 wt = tw[k << (8 - st)];
            float2* sc_ = s + c * LDS_STRIDE;
            float2 a = sc_[j0];
            float2 bb = cmul(sc_[j0 + half], wt);
            sc_[j0]        = make_float2(a.x + bb.x, a.y + bb.y);
            sc_[j0 + half] = make_float2(a.x - bb.x, a.y - bb.y);
        }
    }
    __syncthreads();

    // ---- x c2, conj, re-bit-reverse for inverse FFT ----
    float2 v[16];
    #pragma unroll
    for (int i = 0; i < 16; ++i) {
        int j = g + 16 * i;
        float2 t = cmul(s[c * LDS_STRIDE + j], c2[j]);
        v[i] = make_float2(t.x, -t.y);
    }
    __syncthreads();
    #pragma unroll
    for (int i = 0; i < 16; ++i) {
        int j = g + 16 * i;
        s[c * LDS_STRIDE + brev8(j)] = v[i];
    }

    // ---- inverse FFT (as conj-fft-conj) ----
    #pragma unroll
    for (int st = 1; st <= 8; ++st) {
        __syncthreads();
        int half = 1 << (st - 1);
        #pragma unroll
        for (int i = 0; i < 8; ++i) {
            int b = g + 16 * i;
            int k = b & (half - 1);
            int j0 = ((b >> (st - 1)) << st) + k;
            float2 wt = tw[k << (8 - st)];
            float2* sc_ = s + c * LDS_STRIDE;
            float2 a = sc_[j0];
            float2 bb = cmul(sc_[j0 + half], wt);
            sc_[j0]        = make_float2(a.x + bb.x, a.y + bb.y);
            sc_[j0 + half] = make_float2(a.x - bb.x, a.y - bb.y);
        }
    }
    __syncthreads();

    // ---- conj, x c1 x scale, fftshift, coalesced store ----
    float sc = scl[0] * (1.0f / (float)NFFT);
    #pragma unroll
    for (int r = 0; r < 16; ++r) {
        int j = g + 16 * r;
        float2 gv = s[c * LDS_STRIDE + j];
        gv.y = -gv.y;
        float2 yv = cmul(gv, c1[j]);
        base[(long long)(j ^ 128) * W_N + c] = make_float2(yv.x * sc, yv.y * sc);
    }
}

// ---------------- K3: magnitude/phase + 1x1 conv -----------------------------
__global__ void mag_ang_conv(const float2* __restrict__ Y,
                             const float* __restrict__ wmat,
                             float* __restrict__ out) {
    __shared__ float wl[C_N * 2 * C_N];  // 32*64 = 2048 floats
    int tid = threadIdx.x;
    for (int i = tid; i < C_N * 2 * C_N; i += 256) wl[i] = wmat[i];
    __syncthreads();

    int p = blockIdx.x * 256 + tid;  // pixel index in B*H*W
    int b = p >> 16;                 // H*W = 65536
    int hw = p & 65535;
    const float2* yb = Y + (long long)b * C_N * (H_N * W_N) + hw;

    float acc[C_N];
    #pragma unroll
    for (int o = 0; o < C_N; ++o) acc[o] = 0.0f;

    for (int c = 0; c < C_N; ++c) {
        float2 v = yb[(long long)c * (H_N * W_N)];
        float mag = sqrtf(v.x * v.x + v.y * v.y);
        float ang = atan2f(v.y, v.x) * (float)(1.0 / PI_D);
        #pragma unroll
        for (int o = 0; o < C_N; ++o)
            acc[o] += wl[o * 64 + c] * mag + wl[o * 64 + C_N + c] * ang;
    }

    float* ob = out + (long long)b * C_N * (H_N * W_N) + hw;
    for (int o = 0; o < C_N; ++o)
        ob[(long long)o * (H_N * W_N)] = acc[o];
}

// ---------------- launch -----------------------------------------------------
extern "C" void kernel_launch(void* const* d_in, const int* in_sizes, int n_in,
                              void* d_out, int out_size, void* d_ws, size_t ws_size,
                              hipStream_t stream) {
    const float* x     = (const float*)d_in[0];
    const float* alpha = (const float*)d_in[1];
    const float* wmat  = (const float*)d_in[2];
    float* out = (float*)d_out;

    char* ws = (char*)d_ws;
    float2* c1  = (float2*)(ws);                 // 256 float2 = 2048 B
    float2* c2  = (float2*)(ws + 2048);          // 256 float2 = 2048 B
    float*  scl = (float*)(ws + 4096);           // 1 float
    float2* Y   = (float2*)(ws + 8192);          // B*C*H*W float2 = 64 MiB

    chirp_init<<<1, 256, 0, stream>>>(alpha, c1, c2, scl);

    int nrows = B_N * C_N * H_N;  // 32768
    frft_rows<<<nrows, 128, 0, stream>>>(x, c1, c2, scl, Y);

    int ntiles = B_N * C_N * (W_N / TILE);  // 2048
    frft_cols_tiled<<<ntiles, 256, 0, stream>>>(Y, c1, c2, scl);

    int npix = B_N * H_N * W_N;   // 262144
    mag_ang_conv<<<npix / 256, 256, 0, stream>>>(Y, wmat, out);
}

// Round 3
// 180.130 us; speedup vs baseline: 2.1594x; 1.4143x over previous
//
#include <hip/hip_runtime.h>
#include <math.h>

// Problem constants (from reference setup_inputs): B=4, C=32, H=W=256
#define B_N 4
#define C_N 32
#define H_N 256
#define W_N 256
#define NFFT 256
#define PI_D 3.14159265358979323846
#define TILE 16
#define LS 257  // float2 stride per sequence: 2*257 mod 32 = 2 -> uniform bank use

__device__ __forceinline__ float2 cmul(float2 a, float2 b) {
    return make_float2(a.x * b.x - a.y * b.y, a.x * b.y + a.y * b.x);
}

__device__ __forceinline__ int rev4(int j) {  // base-4 digit reversal, 4 digits
    return ((j & 3) << 6) | (((j >> 2) & 3) << 4) | (((j >> 4) & 3) << 2) | ((j >> 6) & 3);
}

// ---------------- K0: tables (double precision, one tiny block) --------------
__global__ void chirp_init(const float* __restrict__ alpha_p,
                           float2* __restrict__ c1, float2* __restrict__ c2r,
                           float2* __restrict__ tw, float* __restrict__ scl) {
    int j = threadIdx.x;  // 0..255
    double a = (double)alpha_p[0];
    a = fmin(fmax(a, 1e-4), 2.0 - 1e-4);
    double alpha = a * PI_D / 2.0;
    double tan_a2 = tan(a * PI_D / 4.0);
    double sin_a = sin(alpha);
    double n = (double)(j - 128);
    double p1 = -PI_D * n * n * tan_a2 / 256.0;
    c1[j] = make_float2((float)cos(p1), (float)sin(p1));
    int jr = rev4(j);
    double nr = (double)(jr - 128);
    double p2 = -PI_D * nr * nr / (256.0 * sin_a);
    c2r[j] = make_float2((float)cos(p2), (float)sin(p2));  // c2 at digit-reversed index
    double pt = -2.0 * PI_D * (double)j / 256.0;
    tw[j] = make_float2((float)cos(pt), (float)sin(pt));
    if (j == 0) scl[0] = (float)(1.0 / sqrt(fabs(sin_a) + 1e-12));
}

// ---------------- FRFT core on 16 sequences in LDS ---------------------------
// In: s[seq][j] = x[j]*c1[j] (natural order). Out: s[seq][j] = conj-ifft-core
// result (natural order), still needs conj * c1 * scale at store time.
// Forward FFT: radix-4 DIF (natural in -> digit-reversed out).
// Mid: storage[p] holds F[rev4(p)]; z = conj(F*c2) lands in place (c2r table).
// Inverse: radix-4 DIT (digit-reversed in -> natural out).
__device__ __forceinline__ void frft_core(float2* __restrict__ s,
                                          const float2* __restrict__ twl,
                                          const float2* __restrict__ c2r,
                                          int tid) {
    int seq = tid & 15;
    int q = tid >> 4;  // 0..15
    float2* sp = s + seq * LS;

    // ---- forward: radix-4 DIF ----
    #pragma unroll
    for (int st = 0; st < 4; ++st) {
        int shift = 6 - 2 * st;   // L = 64,16,4,1
        int L = 1 << shift;
        int f = 64 >> shift;      // 256/(4L)
        __syncthreads();
        #pragma unroll
        for (int i = 0; i < 4; ++i) {
            int b = q + 16 * i;
            int k = b & (L - 1);
            int base = ((b >> shift) << (shift + 2)) + k;
            float2 a0 = sp[base];
            float2 a1 = sp[base + L];
            float2 a2 = sp[base + 2 * L];
            float2 a3 = sp[base + 3 * L];
            float2 t0 = make_float2(a0.x + a2.x, a0.y + a2.y);
            float2 t1 = make_float2(a0.x - a2.x, a0.y - a2.y);
            float2 t2 = make_float2(a1.x + a3.x, a1.y + a3.y);
            float2 t3 = make_float2(a1.x - a3.x, a1.y - a3.y);
            float2 c0  = make_float2(t0.x + t2.x, t0.y + t2.y);
            float2 cm1 = make_float2(t1.x + t3.y, t1.y - t3.x);  // t1 - i*t3
            float2 cm2 = make_float2(t0.x - t2.x, t0.y - t2.y);
            float2 cm3 = make_float2(t1.x - t3.y, t1.y + t3.x);  // t1 + i*t3
            sp[base]         = c0;
            sp[base + L]     = cmul(cm1, twl[k * f]);
            sp[base + 2 * L] = cmul(cm2, twl[2 * k * f]);
            sp[base + 3 * L] = cmul(cm3, twl[3 * k * f]);
        }
    }
    __syncthreads();

    // ---- mid: elementwise, in place ----
    #pragma unroll
    for (int i = 0; i < 16; ++i) {
        int p = q + 16 * i;
        float2 v = cmul(sp[p], c2r[p]);
        sp[p] = make_float2(v.x, -v.y);
    }

    // ---- inverse core: radix-4 DIT ----
    #pragma unroll
    for (int st = 0; st < 4; ++st) {
        int L = 1 << (2 * st);    // 1,4,16,64
        int f = 64 >> (2 * st);
        __syncthreads();
        #pragma unroll
        for (int i = 0; i < 4; ++i) {
            int b = q + 16 * i;
            int k = b & (L - 1);
            int base = ((b >> (2 * st)) << (2 * st + 2)) + k;
            float2 a0 = sp[base];
            float2 a1 = cmul(sp[base + L],     twl[k * f]);
            float2 a2 = cmul(sp[base + 2 * L], twl[2 * k * f]);
            float2 a3 = cmul(sp[base + 3 * L], twl[3 * k * f]);
            float2 t0 = make_float2(a0.x + a2.x, a0.y + a2.y);
            float2 t1 = make_float2(a0.x - a2.x, a0.y - a2.y);
            float2 t2 = make_float2(a1.x + a3.x, a1.y + a3.y);
            float2 t3 = make_float2(a1.x - a3.x, a1.y - a3.y);
            sp[base]         = make_float2(t0.x + t2.x, t0.y + t2.y);
            sp[base + L]     = make_float2(t1.x + t3.y, t1.y - t3.x);
            sp[base + 2 * L] = make_float2(t0.x - t2.x, t0.y - t2.y);
            sp[base + 3 * L] = make_float2(t1.x - t3.y, t1.y + t3.x);
        }
    }
    __syncthreads();
}

// ---------------- K1: FRFT along W (rows): 16 rows per block -----------------
__global__ __launch_bounds__(256) void frft_rows(
        const float* __restrict__ x,
        const float2* __restrict__ c1, const float2* __restrict__ c2r,
        const float2* __restrict__ twg, const float* __restrict__ scl,
        float2* __restrict__ Y) {
    __shared__ float2 s[TILE * LS];
    __shared__ float2 twl[NFFT];
    int tid = threadIdx.x;
    twl[tid] = twg[tid];

    long long row0 = (long long)blockIdx.x * TILE;
    const float* xb = x + row0 * NFFT;
    int j = tid;  // natural element index
    float2 c1j = c1[j];

    #pragma unroll
    for (int r = 0; r < TILE; ++r) {
        float xv = xb[r * NFFT + (j ^ 128)];  // ifftshift
        s[r * LS + j] = make_float2(xv * c1j.x, xv * c1j.y);
    }

    frft_core(s, twl, c2r, tid);

    float sc = scl[0] * (1.0f / 256.0f);
    float2* Yb = Y + row0 * NFFT;
    #pragma unroll
    for (int r = 0; r < TILE; ++r) {
        float2 g = s[r * LS + j];
        g.y = -g.y;                            // conj -> completes ifft
        float2 yv = cmul(g, c1j);
        Yb[r * NFFT + (j ^ 128)] = make_float2(yv.x * sc, yv.y * sc);  // fftshift
    }
}

// ---------------- K2: FRFT along H (cols): 16 cols per block -----------------
__global__ __launch_bounds__(256) void frft_cols(
        float2* __restrict__ Y,
        const float2* __restrict__ c1, const float2* __restrict__ c2r,
        const float2* __restrict__ twg, const float* __restrict__ scl) {
    __shared__ float2 s[TILE * LS];
    __shared__ float2 twl[NFFT];
    int tid = threadIdx.x;
    twl[tid] = twg[tid];

    int c = tid & 15;
    int g = tid >> 4;  // 0..15
    int blk = blockIdx.x;
    int w0 = (blk & 15) << 4;
    long long bc = blk >> 4;
    float2* base = Y + bc * (long long)(H_N * W_N) + w0 + c;

    #pragma unroll
    for (int r = 0; r < TILE; ++r) {
        int j = g + 16 * r;
        float2 xv = base[(long long)(j ^ 128) * W_N];
        s[c * LS + j] = cmul(xv, c1[j]);
    }

    frft_core(s, twl, c2r, tid);

    float sc = scl[0] * (1.0f / 256.0f);
    #pragma unroll
    for (int r = 0; r < TILE; ++r) {
        int j = g + 16 * r;
        float2 gv = s[c * LS + j];
        gv.y = -gv.y;
        float2 yv = cmul(gv, c1[j]);
        base[(long long)(j ^ 128) * W_N] = make_float2(yv.x * sc, yv.y * sc);
    }
}

// ---------------- K3: magnitude/phase + 1x1 conv -----------------------------
__device__ __forceinline__ float fast_atan2(float y, float x) {
    float ax = fabsf(x), ay = fabsf(y);
    float mx = fmaxf(ax, ay), mn = fminf(ax, ay);
    float z = mn * __builtin_amdgcn_rcpf(fmaxf(mx, 1e-37f));
    float z2 = z * z;
    // minimax atan(z) on [0,1], |err| ~1e-6
    float p = fmaf(z2, -0.01172120f, 0.05265332f);
    p = fmaf(z2, p, -0.11643287f);
    p = fmaf(z2, p, 0.19354346f);
    p = fmaf(z2, p, -0.33262347f);
    p = fmaf(z2, p, 0.99997726f);
    p = p * z;
    float r = (ay > ax) ? (1.5707963f - p) : p;
    r = (x < 0.0f) ? (3.14159265f - r) : r;
    return copysignf(r, y);
}

__global__ __launch_bounds__(256) void mag_ang_conv(
        const float2* __restrict__ Y,
        const float* __restrict__ wmat,
        float* __restrict__ out) {
    int p = blockIdx.x * 256 + threadIdx.x;  // pixel in B*H*W
    int b = p >> 16;
    int hw = p & 65535;
    const float2* yb = Y + ((long long)b << 21) + hw;  // b*C*H*W

    float mag[C_N], ang[C_N];
    #pragma unroll
    for (int c = 0; c < C_N; ++c) {
        float2 v = yb[(long long)c << 16];
        mag[c] = sqrtf(fmaf(v.x, v.x, v.y * v.y));
        ang[c] = fast_atan2(v.y, v.x) * 0.31830988618f;  // 1/pi
    }

    float* ob = out + ((long long)b << 21) + hw;
    #pragma unroll
    for (int o = 0; o < C_N; ++o) {
        float acc = 0.0f;
        #pragma unroll
        for (int c = 0; c < C_N; ++c) {
            acc = fmaf(wmat[o * 64 + c], mag[c], acc);       // uniform -> s_load
            acc = fmaf(wmat[o * 64 + 32 + c], ang[c], acc);
        }
        ob[(long long)o << 16] = acc;
    }
}

// ---------------- launch -----------------------------------------------------
extern "C" void kernel_launch(void* const* d_in, const int* in_sizes, int n_in,
                              void* d_out, int out_size, void* d_ws, size_t ws_size,
                              hipStream_t stream) {
    const float* x     = (const float*)d_in[0];
    const float* alpha = (const float*)d_in[1];
    const float* wmat  = (const float*)d_in[2];
    float* out = (float*)d_out;

    char* ws = (char*)d_ws;
    float2* c1  = (float2*)(ws);           // 2048 B
    float2* c2r = (float2*)(ws + 2048);    // 2048 B
    float2* tw  = (float2*)(ws + 4096);    // 2048 B
    float*  scl = (float*)(ws + 6144);     // 4 B
    float2* Y   = (float2*)(ws + 8192);    // 64 MiB

    chirp_init<<<1, 256, 0, stream>>>(alpha, c1, c2r, tw, scl);

    frft_rows<<<B_N * C_N * H_N / TILE, 256, 0, stream>>>(x, c1, c2r, tw, scl, Y);
    frft_cols<<<B_N * C_N * (W_N / TILE), 256, 0, stream>>>(Y, c1, c2r, tw, scl);

    mag_ang_conv<<<B_N * H_N * W_N / 256, 256, 0, stream>>>(Y, wmat, out);
}

// Round 4
// 155.208 us; speedup vs baseline: 2.5062x; 1.1606x over previous
//
#include <hip/hip_runtime.h>
#include <math.h>

// Problem constants (from reference setup_inputs): B=4, C=32, H=W=256
#define B_N 4
#define C_N 32
#define H_N 256
#define W_N 256
#define PI_D 3.14159265358979323846
#define LSQ 257  // float2 stride per sequence in LDS

__device__ __forceinline__ float2 cmul(float2 a, float2 b) {
    return make_float2(a.x * b.x - a.y * b.y, a.x * b.y + a.y * b.x);
}
__device__ __forceinline__ float2 f2add(float2 a, float2 b) {
    return make_float2(a.x + b.x, a.y + b.y);
}
__device__ __forceinline__ float2 f2sub(float2 a, float2 b) {
    return make_float2(a.x - b.x, a.y - b.y);
}

// ---------------- K0: tables -------------------------------------------------
// c1[j], c2[j] natural order; twm[16*k1 + t] = W256^{t*k1}; scl.
__global__ void chirp_init(const float* __restrict__ alpha_p,
                           float2* __restrict__ c1, float2* __restrict__ c2,
                           float2* __restrict__ twm, float* __restrict__ scl) {
    int j = threadIdx.x;  // 0..255
    double a = fmin(fmax((double)alpha_p[0], 1e-4), 2.0 - 1e-4);
    double tan_a2 = tan(a * PI_D / 4.0);
    double sin_a  = sin(a * PI_D / 2.0);   // > 0 for a in (0,2)
    double n = (double)(j - 128);
    float sn, cs;

    double u1 = n * n * tan_a2 * (1.0 / 256.0);       // phase = -pi*u1
    u1 -= 2.0 * floor(u1 * 0.5);                      // mod 2
    __sincosf((float)(-PI_D * u1), &sn, &cs);
    c1[j] = make_float2(cs, sn);

    double u2 = n * n / (256.0 * sin_a);
    u2 -= 2.0 * floor(u2 * 0.5);
    __sincosf((float)(-PI_D * u2), &sn, &cs);
    c2[j] = make_float2(cs, sn);

    int k1 = j >> 4, t = j & 15;
    __sincosf((float)(-2.0 * PI_D * (double)(t * k1) / 256.0), &sn, &cs);
    twm[j] = make_float2(cs, sn);

    if (j == 0) scl[0] = (float)(1.0 / sqrt(fabs(sin_a) + 1e-12));
}

// ---------------- FFT16 in registers (radix-4 x radix-4) ---------------------
// Input: v[n] natural order. Output: v[4*(k&3) + (k>>2)] = F[k].
// Forward: W = e^{-2pi i/16}; INV: conjugated (no scaling).
template <bool INV>
__device__ __forceinline__ void fft16(float2* v) {
    const float C1 = 0.9238795325112867f, S1 = 0.3826834323650898f;
    const float C2 = 0.7071067811865476f;
    const float2 tw1 = make_float2(C1, INV ? S1 : -S1);
    const float2 tw2 = make_float2(C2, INV ? C2 : -C2);
    const float2 tw3 = make_float2(S1, INV ? C1 : -C1);
    const float2 tw4 = make_float2(0.0f, INV ? 1.0f : -1.0f);
    const float2 tw6 = make_float2(-C2, INV ? C2 : -C2);
    const float2 tw9 = make_float2(-C1, INV ? -S1 : S1);
    float2 u[16];
    #pragma unroll
    for (int n2 = 0; n2 < 4; ++n2) {
        float2 e0 = v[n2], e1 = v[4 + n2], e2 = v[8 + n2], e3 = v[12 + n2];
        float2 t0 = f2add(e0, e2), t1 = f2sub(e0, e2);
        float2 t2 = f2add(e1, e3), t3 = f2sub(e1, e3);
        float2 A0 = f2add(t0, t2);
        float2 A2 = f2sub(t0, t2);
        float2 A1, A3;
        if (!INV) { A1 = make_float2(t1.x + t3.y, t1.y - t3.x);
                    A3 = make_float2(t1.x - t3.y, t1.y + t3.x); }
        else      { A1 = make_float2(t1.x - t3.y, t1.y + t3.x);
                    A3 = make_float2(t1.x + t3.y, t1.y - t3.x); }
        u[n2] = A0;
        if (n2 == 0) { u[4 + n2] = A1;            u[8 + n2] = A2;            u[12 + n2] = A3; }
        if (n2 == 1) { u[4 + n2] = cmul(A1, tw1); u[8 + n2] = cmul(A2, tw2); u[12 + n2] = cmul(A3, tw3); }
        if (n2 == 2) { u[4 + n2] = cmul(A1, tw2); u[8 + n2] = cmul(A2, tw4); u[12 + n2] = cmul(A3, tw6); }
        if (n2 == 3) { u[4 + n2] = cmul(A1, tw3); u[8 + n2] = cmul(A2, tw6); u[12 + n2] = cmul(A3, tw9); }
    }
    #pragma unroll
    for (int k1 = 0; k1 < 4; ++k1) {
        float2 e0 = u[4 * k1], e1 = u[4 * k1 + 1], e2 = u[4 * k1 + 2], e3 = u[4 * k1 + 3];
        float2 t0 = f2add(e0, e2), t1 = f2sub(e0, e2);
        float2 t2 = f2add(e1, e3), t3 = f2sub(e1, e3);
        v[4 * k1 + 0] = f2add(t0, t2);
        v[4 * k1 + 2] = f2sub(t0, t2);
        if (!INV) { v[4 * k1 + 1] = make_float2(t1.x + t3.y, t1.y - t3.x);
                    v[4 * k1 + 3] = make_float2(t1.x - t3.y, t1.y + t3.x); }
        else      { v[4 * k1 + 1] = make_float2(t1.x - t3.y, t1.y + t3.x);
                    v[4 * k1 + 3] = make_float2(t1.x + t3.y, t1.y - t3.x); }
    }
}
#define REG(k) (4 * ((k) & 3) + ((k) >> 2))

// ---------------- FRFT core: 256-pt via four-step radix-16 -------------------
// In: v[n1] = x[16*n1 + t] * c1[16*n1 + t]. Out: v[REG(m1)] = z[16*m1 + t]
// where z = ifft( fft(x*c1) * c2 ) * 256 (caller applies 1/256 in scale).
// sp: this sequence's 16x16 LDS matrix, XOR-swizzled: (row r, col c) at
// sp[16*r + (c ^ r)].
__device__ __forceinline__ void frft_core16(float2* v, float2* __restrict__ sp,
                                            int t,
                                            const float2* __restrict__ c2l,
                                            const float2* __restrict__ twl) {
    fft16<false>(v);  // over n1 -> A[k1] at v[REG(k1)]
    float2 w[16];
    #pragma unroll
    for (int k1 = 0; k1 < 16; ++k1)
        w[k1] = cmul(v[REG(k1)], twl[16 * k1 + t]);   // * W256^{t*k1}
    #pragma unroll
    for (int k1 = 0; k1 < 16; ++k1)
        sp[16 * k1 + (t ^ k1)] = w[k1];               // M[k1][t]
    __syncthreads();
    #pragma unroll
    for (int n2 = 0; n2 < 16; ++n2)
        v[n2] = sp[16 * t + (n2 ^ t)];                // M[t][n2]
    fft16<false>(v);  // over n2 -> B[k2] = X[t + 16*k2] at v[REG(k2)]
    #pragma unroll
    for (int k2 = 0; k2 < 16; ++k2)
        w[k2] = cmul(v[REG(k2)], c2l[t + 16 * k2]);   // mid: * c2
    fft16<true>(w);   // over k2 -> C[m2] at w[REG(m2)]
    __syncthreads();  // all phase-1 reads done before overwrite
    #pragma unroll
    for (int m2 = 0; m2 < 16; ++m2) {
        float2 tw = twl[16 * m2 + t];
        tw.y = -tw.y;                                 // W256^{+t*m2}
        sp[16 * m2 + (t ^ m2)] = cmul(w[REG(m2)], tw);
    }
    __syncthreads();
    #pragma unroll
    for (int k1 = 0; k1 < 16; ++k1)
        v[k1] = sp[16 * t + (k1 ^ t)];
    fft16<true>(v);   // over k1 -> z[16*m1 + t] at v[REG(m1)]
}

// ---------------- K1: FRFT along W (rows): 16 rows per block -----------------
__global__ __launch_bounds__(256) void frft_rows(
        const float* __restrict__ x,
        const float2* __restrict__ c1, const float2* __restrict__ c2,
        const float2* __restrict__ twm, const float* __restrict__ scl,
        float2* __restrict__ Y) {
    __shared__ float2 s[16 * LSQ];
    __shared__ float2 c1l[256], c2l[256], twl[256];
    int tid = threadIdx.x;
    int t = tid & 15, seq = tid >> 4;
    c1l[tid] = c1[tid]; c2l[tid] = c2[tid]; twl[tid] = twm[tid];

    long long row = (long long)blockIdx.x * 16 + seq;
    const float* xr = x + row * 256;
    float xs[16];
    #pragma unroll
    for (int n1 = 0; n1 < 16; ++n1)
        xs[n1] = xr[16 * (n1 ^ 8) + t];   // ifftshift
    __syncthreads();

    float2 v[16];
    #pragma unroll
    for (int n1 = 0; n1 < 16; ++n1) {
        float2 c = c1l[16 * n1 + t];
        v[n1] = make_float2(xs[n1] * c.x, xs[n1] * c.y);
    }

    frft_core16(v, s + seq * LSQ, t, c2l, twl);

    float sc = scl[0] * (1.0f / 256.0f);
    float2* Yr = Y + row * 256;
    #pragma unroll
    for (int m1 = 0; m1 < 16; ++m1) {
        float2 o = cmul(v[REG(m1)], c1l[16 * m1 + t]);
        Yr[16 * (m1 ^ 8) + t] = make_float2(o.x * sc, o.y * sc);  // fftshift
    }
}

// ---------------- K2: FRFT along H (cols): 16 cols per block -----------------
__global__ __launch_bounds__(256) void frft_cols(
        float2* __restrict__ Y,
        const float2* __restrict__ c1, const float2* __restrict__ c2,
        const float2* __restrict__ twm, const float* __restrict__ scl) {
    __shared__ float2 s[16 * LSQ];
    __shared__ float2 c1l[256], c2l[256], twl[256];
    int tid = threadIdx.x;
    int seqc = tid & 15, t = tid >> 4;
    c1l[tid] = c1[tid]; c2l[tid] = c2[tid]; twl[tid] = twm[tid];

    int blk = blockIdx.x;
    int w0 = (blk & 15) << 4;
    long long bc = blk >> 4;
    float2* base = Y + bc * (long long)(H_N * W_N) + w0 + seqc;

    float2 v[16];
    #pragma unroll
    for (int n1 = 0; n1 < 16; ++n1)
        v[n1] = base[(long long)(16 * (n1 ^ 8) + t) * W_N];
    __syncthreads();
    #pragma unroll
    for (int n1 = 0; n1 < 16; ++n1)
        v[n1] = cmul(v[n1], c1l[16 * n1 + t]);

    frft_core16(v, s + seqc * LSQ, t, c2l, twl);

    float sc = scl[0] * (1.0f / 256.0f);
    #pragma unroll
    for (int m1 = 0; m1 < 16; ++m1) {
        float2 o = cmul(v[REG(m1)], c1l[16 * m1 + t]);
        base[(long long)(16 * (m1 ^ 8) + t) * W_N] = make_float2(o.x * sc, o.y * sc);
    }
}

// ---------------- K3: magnitude/phase + 1x1 conv -----------------------------
__device__ __forceinline__ float fast_atan2(float y, float x) {
    float ax = fabsf(x), ay = fabsf(y);
    float mx = fmaxf(ax, ay), mn = fminf(ax, ay);
    float z = mn * __builtin_amdgcn_rcpf(fmaxf(mx, 1e-37f));
    float z2 = z * z;
    float p = fmaf(z2, -0.01172120f, 0.05265332f);
    p = fmaf(z2, p, -0.11643287f);
    p = fmaf(z2, p, 0.19354346f);
    p = fmaf(z2, p, -0.33262347f);
    p = fmaf(z2, p, 0.99997726f);
    p = p * z;
    float r = (ay > ax) ? (1.5707963f - p) : p;
    r = (x < 0.0f) ? (3.14159265f - r) : r;
    return copysignf(r, y);
}

__global__ __launch_bounds__(256) void mag_ang_conv(
        const float2* __restrict__ Y,
        const float* __restrict__ wmat,
        float* __restrict__ out) {
    int p = blockIdx.x * 256 + threadIdx.x;  // pixel in B*H*W
    int b = p >> 16;
    int hw = p & 65535;
    const float2* yb = Y + ((long long)b << 21) + hw;

    float mag[C_N], ang[C_N];
    #pragma unroll
    for (int c = 0; c < C_N; ++c) {
        float2 v = yb[(long long)c << 16];
        mag[c] = sqrtf(fmaf(v.x, v.x, v.y * v.y));
        ang[c] = fast_atan2(v.y, v.x) * 0.31830988618f;  // 1/pi
    }

    float* ob = out + ((long long)b << 21) + hw;
    #pragma unroll
    for (int o = 0; o < C_N; ++o) {
        float acc = 0.0f;
        #pragma unroll
        for (int c = 0; c < C_N; ++c) {
            acc = fmaf(wmat[o * 64 + c], mag[c], acc);
            acc = fmaf(wmat[o * 64 + 32 + c], ang[c], acc);
        }
        ob[(long long)o << 16] = acc;
    }
}

// ---------------- launch -----------------------------------------------------
extern "C" void kernel_launch(void* const* d_in, const int* in_sizes, int n_in,
                              void* d_out, int out_size, void* d_ws, size_t ws_size,
                              hipStream_t stream) {
    const float* x     = (const float*)d_in[0];
    const float* alpha = (const float*)d_in[1];
    const float* wmat  = (const float*)d_in[2];
    float* out = (float*)d_out;

    char* ws = (char*)d_ws;
    float2* c1  = (float2*)(ws);           // 2048 B
    float2* c2  = (float2*)(ws + 2048);    // 2048 B
    float2* twm = (float2*)(ws + 4096);    // 2048 B
    float*  scl = (float*)(ws + 6144);     // 4 B
    float2* Y   = (float2*)(ws + 8192);    // 64 MiB

    chirp_init<<<1, 256, 0, stream>>>(alpha, c1, c2, twm, scl);

    frft_rows<<<B_N * C_N * H_N / 16, 256, 0, stream>>>(x, c1, c2, twm, scl, Y);
    frft_cols<<<B_N * C_N * (W_N / 16), 256, 0, stream>>>(Y, c1, c2, twm, scl);

    mag_ang_conv<<<B_N * H_N * W_N / 256, 256, 0, stream>>>(Y, wmat, out);
}